// Round 8
// baseline (369.214 us; speedup 1.0000x reference)
//
#include <hip/hip_runtime.h>
#include <hip/hip_cooperative_groups.h>
#include <stdint.h>
#include <math.h>

namespace cg = cooperative_groups;

// Validated semantics (r17/r18 green): printed reference, fp32 in/out.
//   p[b,j] = mean_h sigmoid(delta/sqrt(32)),
//   delta[j,b,h] = sum_e D_e*(U+V),  D_e = (s_e-mu_s)-(o_e-mu_o)
//   Folded mu: sum_e D*w = sum_e (s-o)*w - ((sum s - sum o)/256)*sum_e w
//   U[h,e,j] = sum_{d in h} QwT[d,j]*Wk[d,e],  QwT = Qp[256+j]@Wq^T
//   V[b,h,e] = sum_{d in h} (Pq[b,d]+bq[d])*Wk[d,e],  Pq = pe[b]@Wq^T
//   new_state[b,e,l<256]=state; l>=256: p*s_l+(1-p)*o_{l-256}
//   atten[b,l,s]: l<256 -> 1 at s=l; else p at s=l, 1-p at s=l+256.
// This round: r7 redistribution was neutral -> the cost is the 4 serialized
// launch/drain boundaries, not per-kernel BW. Fuse all 5 kernels into ONE
// cooperative kernel (512 blocks x 256, 2 blocks/CU by LDS) with 4
// grid.sync()s. Phase bodies byte-copied from the verified r6/r7 kernels;
// static 59 MB output spread into phases A/B/D as fill work.

// d_ws layout (floats) — unchanged
#define WS_P    0        // [32 b][256 j]  sum_h sigmoid
#define WS_QWT  8192     // [256 d][256 j]
#define WS_PQ   73728    // [32 b][256 d]
#define WS_U    81920    // [8 h][256 e][256 j]
#define WS_V    606208   // [32 b][8 h][256 e]
#define WS_QPT  671744   // [256 e][256 j]  QpT[e][j] = Qp[256+j][e]
#define WS_WQT  737280   // [256 e][256 d]  WqT[e][d] = Wq[d][e]

typedef float vf4 __attribute__((ext_vector_type(4)));
__device__ __forceinline__ void nt_store4(float* p, float x, float y,
                                          float z, float w) {
  vf4 v; v.x = x; v.y = y; v.z = z; v.w = w;
  __builtin_nontemporal_store(v, (vf4*)p);
}

// P-independent output, one flat f4 index space (mappings identical to r7):
//   [0, 1572864):        identity-atten rows l<256 (one-hot at s=l)
//   [1572864, 3145728):  zero body of atten rows l>=256 (diag fixed in E)
//   [3145728, 3670016):  new_state identity half (state cols 0..255)
__device__ __forceinline__ void write_static(int idx, const float* __restrict__ state,
                                             float* __restrict__ out) {
  if (idx < 1572864) {
    int g4 = idx;
    int row_id = g4 / 192, c = g4 - row_id * 192;
    int b = row_id >> 8, l = row_id & 255;
    float v[4] = {0.f, 0.f, 0.f, 0.f};
    int s0 = c << 2;
    if (l >= s0 && l < s0 + 4) v[l - s0] = 1.0f;
    nt_store4(out + 4194304 + (size_t)((b << 9) + l) * 768 + (c << 2),
              v[0], v[1], v[2], v[3]);
  } else if (idx < 3145728) {
    int g4 = idx - 1572864;
    int row_id = g4 / 192, c = g4 - row_id * 192;
    int b = row_id >> 8, l = 256 + (row_id & 255);
    nt_store4(out + 4194304 + (size_t)((b << 9) + l) * 768 + (c << 2),
              0.f, 0.f, 0.f, 0.f);
  } else {
    int g4 = idx - 3145728;             // 0..524287
    int row = g4 >> 6, c = g4 & 63;     // row = b*256+e, cols l = 4c..4c+3
    float4 sv = ((const float4*)state)[(size_t)row * 128 + c];
    nt_store4(out + (size_t)row * 512 + (c << 2), sv.x, sv.y, sv.z, sv.w);
  }
}

// ---------------------------------------------------------------------------
// Mega-kernel: 512 blocks x 256 threads, 5 phases, 4 grid syncs.
// LDS: one 14848-float (59.4 KB) arena -> 2 blocks/CU (118.8 of 160 KB).
__global__ void __launch_bounds__(256, 2)
mega(const float* __restrict__ state, const float* __restrict__ obs,
     const float* __restrict__ Qp, const float* __restrict__ Wq,
     const float* __restrict__ Wk, const float* __restrict__ bq,
     float* __restrict__ ws, float* __restrict__ out) {
  cg::grid_group grid = cg::this_grid();
  __shared__ float S[14848];
  int bid = blockIdx.x, t = threadIdx.x;

  // ---- Phase A: QpT/WqT transposes (128) || static [0, 1433600) (384) ----
  if (bid < 128) {
    float (*tile)[33] = (float(*)[33])S;
    const float* src; float* dst; int ti;
    if (bid < 64) { src = Qp + 65536; dst = ws + WS_QPT; ti = bid; }
    else          { src = Wq;         dst = ws + WS_WQT; ti = bid - 64; }
    int tr = ti >> 3, tc = ti & 7;
    int c = t & 31, r0 = t >> 5;
    #pragma unroll
    for (int k = 0; k < 4; ++k) {
      int r = r0 + (k << 3);
      tile[r][c] = src[(size_t)(tr * 32 + r) * 256 + tc * 32 + c];
    }
    __syncthreads();
    #pragma unroll
    for (int k = 0; k < 4; ++k) {
      int r = r0 + (k << 3);
      dst[(size_t)(tc * 32 + r) * 256 + tr * 32 + c] = tile[c][r];
    }
  } else {
    for (int i = ((bid - 128) << 8) + t; i < 1433600; i += 98304)
      write_static(i, state, out);
  }
  grid.sync();

  // ---- Phase B: QwT/Pq matvecs (288) || static [1433600, 2662400) (224) --
  if (bid < 288) {
    float* lvec = S;
    const float* __restrict__ GT; float* dst;
    if (bid < 256) {                    // QwT[d][j] = sum_e Wq[d][e]*QpT[e][j]
      int d = bid;
      lvec[t] = Wq[(size_t)d * 256 + t];
      GT = ws + WS_QPT; dst = ws + WS_QWT + d * 256;
    } else {                            // Pq[b][d] = sum_e pe[b][e]*WqT[e][d]
      int b = bid - 256;
      int k2 = t & ~1;                  // arange value 2k
      float div = expf((float)k2 * (-9.210340371976184f / 256.f));
      float a = (float)b * div;
      lvec[t] = (t & 1) ? cosf(a) : sinf(a);
      GT = ws + WS_WQT; dst = ws + WS_PQ + b * 256;
    }
    __syncthreads();
    float acc = 0.f;
    #pragma unroll 8
    for (int e = 0; e < 256; ++e)
      acc += lvec[e] * GT[(e << 8) + t];
    dst[t] = acc;
  } else {
    for (int i = 1433600 + ((bid - 288) << 8) + t; i < 2662400; i += 57344)
      write_static(i, state, out);
  }
  grid.sync();

  // ---- Phase C: U (256) + V (256), all blocks busy ------------------------
  if (bid < 256) {
    int h = bid >> 5, e0 = (bid & 31) << 3;
    float* wk_s = S;                    // [32][9] padded
    {
      int d = t >> 3, i = t & 7;
      wk_s[d * 9 + i] = Wk[(size_t)(h * 32 + d) * 256 + e0 + i];
    }
    __syncthreads();
    float acc[8] = {0.f, 0.f, 0.f, 0.f, 0.f, 0.f, 0.f, 0.f};
    const float* __restrict__ Qw = ws + WS_QWT + t;
    #pragma unroll 4
    for (int d = 0; d < 32; ++d) {
      float q = Qw[((h << 5) + d) << 8];
      #pragma unroll
      for (int i = 0; i < 8; ++i) acc[i] += wk_s[d * 9 + i] * q;
    }
    float* Uh = ws + WS_U + (h << 16) + (size_t)e0 * 256;
    #pragma unroll
    for (int i = 0; i < 8; ++i) Uh[(size_t)i * 256 + t] = acc[i];
  } else {
    int idx = bid - 256, b = idx >> 3, h = idx & 7;
    float acc = 0.f;
    #pragma unroll 8
    for (int dd = 0; dd < 32; ++dd) {
      int d = h * 32 + dd;
      acc += (ws[WS_PQ + b * 256 + d] + bq[d]) * Wk[(size_t)d * 256 + t];
    }
    ws[WS_V + ((b << 3) + h) * 256 + t] = acc;
  }
  grid.sync();

  // ---- Phase D: delta->P (256) || static [2662400, 3670016) (256) --------
  if (bid < 256) {
    int b = bid >> 3, jt = (bid & 7) << 5;
    float* Xs = S;                      // [256][33]
    float* Vs = S + 8448;               // [2048]
    float* pd = S + 10496;              // [8][8][32]
    float* pw = S + 12544;              // [8][8][32]
    float* px = S + 14592;              // [8][32]
    {
      int es = t >> 3, jq = t & 7;
      const float* sp = state + (size_t)b * 131072 + 256 + jt + (jq << 2);
      const float* op = obs   + (size_t)b * 65536  + jt + (jq << 2);
      #pragma unroll
      for (int k = 0; k < 8; ++k) {
        int e = es + (k << 5);
        float4 s4 = *(const float4*)(sp + (size_t)e * 512);
        float4 o4 = *(const float4*)(op + (size_t)e * 256);
        float* xr = Xs + e * 33 + (jq << 2);
        xr[0] = s4.x - o4.x; xr[1] = s4.y - o4.y;
        xr[2] = s4.z - o4.z; xr[3] = s4.w - o4.w;
      }
      for (int i = t; i < 2048; i += 256) Vs[i] = ws[WS_V + (b << 11) + i];
    }
    __syncthreads();
    int j = t & 31, eg = t >> 5, e0 = eg << 5;
    {
      float ax = 0.f;
      #pragma unroll
      for (int ei = 0; ei < 32; ++ei) ax += Xs[(e0 + ei) * 33 + j];
      px[eg * 32 + j] = ax;
    }
    const float* __restrict__ Ub = ws + WS_U + jt + j;
    #pragma unroll
    for (int h = 0; h < 8; ++h) {
      float dacc = 0.f, wacc = 0.f;
      const float* __restrict__ Uh = Ub + (h << 16) + (e0 << 8);
      const float* __restrict__ Vh = Vs + (h << 8) + e0;
      #pragma unroll 16
      for (int ei = 0; ei < 32; ++ei) {
        float w = Uh[ei << 8] + Vh[ei];
        dacc += Xs[(e0 + ei) * 33 + j] * w;
        wacc += w;
      }
      pd[((eg << 3) + h) * 32 + j] = dacc;
      pw[((eg << 3) + h) * 32 + j] = wacc;
    }
    __syncthreads();
    int h2 = t >> 5, j2 = t & 31;
    float D = 0.f, W = 0.f, X = 0.f;
    #pragma unroll
    for (int g = 0; g < 8; ++g) {
      D += pd[((g << 3) + h2) * 32 + j2];
      W += pw[((g << 3) + h2) * 32 + j2];
      X += px[g * 32 + j2];
    }
    float delta = D - X * (1.f / 256.f) * W;
    float sig = 1.f / (1.f + __expf(-delta * 0.17677669529663687f)); // /sqrt(32)
    __syncthreads();
    px[h2 * 32 + j2] = sig;             // reuse px as [h][j] sigmoid buffer
    __syncthreads();
    if (t < 32) {
      float acc = 0.f;
      #pragma unroll
      for (int h = 0; h < 8; ++h) acc += px[h * 32 + t];
      ws[WS_P + (b << 8) + jt + t] = acc;   // sum_h; E applies *0.125
    }
  } else {
    for (int i = 2662400 + ((bid - 256) << 8) + t; i < 3670016; i += 65536)
      write_static(i, state, out);
  }
  grid.sync();

  // ---- Phase E: P-dependent merge (all 512) + atten diagonal (32) --------
  #pragma unroll
  for (int k = 0; k < 4; ++k) {
    int gi = (bid << 10) + (k << 8) + t;  // 0..524287
    int row = gi >> 6, c = gi & 63;       // row = b*256+e, upper-half f4 c
    int b = row >> 8;
    float4 sv = ((const float4*)(state + (size_t)row * 512))[64 + c];
    float4 ov = ((const float4*)(obs + (size_t)row * 256))[c];
    float4 p4 = ((const float4*)(ws + WS_P + b * 256))[c];
    p4.x *= 0.125f; p4.y *= 0.125f; p4.z *= 0.125f; p4.w *= 0.125f;
    nt_store4(out + (size_t)row * 512 + 256 + (c << 2),
              p4.x * sv.x + (1.f - p4.x) * ov.x,
              p4.y * sv.y + (1.f - p4.y) * ov.y,
              p4.z * sv.z + (1.f - p4.z) * ov.z,
              p4.w * sv.w + (1.f - p4.w) * ov.w);
  }
  if (bid < 32) {                       // diag of pre-zeroed l>=256 rows
    int idx = (bid << 8) + t;           // 0..8191
    int b = idx >> 8, j = idx & 255;
    float p = ws[WS_P + (b << 8) + j] * 0.125f;
    size_t r = 4194304 + (size_t)((b << 9) + 256 + j) * 768;
    out[r + 256 + j] = p;               // s = l
    out[r + 512 + j] = 1.f - p;         // s = l + 256
  }
}

extern "C" void kernel_launch(void* const* d_in, const int* in_sizes, int n_in,
                              void* d_out, int out_size, void* d_ws, size_t ws_size,
                              hipStream_t stream) {
  const float *state = nullptr, *obs = nullptr, *Qp = nullptr;
  const float *Wq = nullptr, *Wk = nullptr, *bq = nullptr, *bk = nullptr;
  for (int i = 0; i < n_in; ++i) {
    int s = in_sizes[i];
    const float* p = (const float*)d_in[i];
    if      (s == 4194304) state = p;
    else if (s == 2097152) obs = p;
    else if (s == 131072)  Qp = p;
    else if (s == 65536)   { if (!Wq) Wq = p; else Wk = p; }
    else if (s == 256)     { if (!bq) bq = p; else bk = p; }
  }
  (void)bk;                             // cancels in the 2-way softmax
  float* out = (float*)d_out;
  float* ws  = (float*)d_ws;

  void* args[] = {(void*)&state, (void*)&obs, (void*)&Qp, (void*)&Wq,
                  (void*)&Wk, (void*)&bq, (void*)&ws, (void*)&out};
  hipLaunchCooperativeKernel((const void*)mega, dim3(512), dim3(256),
                             args, 0, stream);
}

// Round 9
// 128.039 us; speedup vs baseline: 2.8836x; 2.8836x over previous
//
#include <hip/hip_runtime.h>
#include <stdint.h>
#include <math.h>

// Validated semantics (r17/r18 green): printed reference, fp32 in/out.
//   p[b,j] = mean_h sigmoid(delta/sqrt(32)),
//   delta[j,b,h] = sum_e D_e*(U+V),  D_e = (s_e-mu_s)-(o_e-mu_o)
//   Folded mu: sum_e D*w = sum_e (s-o)*w - ((sum s - sum o)/256)*sum_e w
//   U[h,e,j] = sum_{d in h} QwT[d,j]*Wk[d,e],  QwT = Qp[256+j]@Wq^T
//   V[b,h,e] = sum_{d in h} (Pq[b,d]+bq[d])*Wk[d,e],  Pq = pe[b]@Wq^T
//   new_state[b,e,l<256]=state; l>=256: p*s_l+(1-p)*o_{l-256}
//   atten[b,l,s]: l<256 -> 1 at s=l; else p at s=l, 1-p at s=l+256.
// r8 post-mortem: cooperative grid.sync costs ~60us/sync across 8 XCDs
// (283us mega, VALUBusy 2.2%) -> launch boundaries are cheaper. Reverted.
// This round: r6 126.56us build + ONE change: k_pro QwT-half does 4 d-rows
// per block (64 blocks), 4 FMAs/load, QPT L2 re-reads 64->16 MB.

// d_ws layout (floats) — unchanged
#define WS_P    0        // [32 b][256 j]  sum_h sigmoid
#define WS_QWT  8192     // [256 d][256 j]
#define WS_PQ   73728    // [32 b][256 d]
#define WS_U    81920    // [8 h][256 e][256 j]
#define WS_V    606208   // [32 b][8 h][256 e]
#define WS_QPT  671744   // [256 e][256 j]  QpT[e][j] = Qp[256+j][e]
#define WS_WQT  737280   // [256 e][256 d]  WqT[e][d] = Wq[d][e]
// end 802816 floats = 3.06 MB (ws is 256 MiB per fill WRITE_SIZE)

typedef float vf4 __attribute__((ext_vector_type(4)));
__device__ __forceinline__ void nt_store4(float* p, float x, float y,
                                          float z, float w) {
  vf4 v; v.x = x; v.y = y; v.z = z; v.w = w;
  __builtin_nontemporal_store(v, (vf4*)p);
}

// ---------------------------------------------------------------------------
// K0 transpose: QpT and WqT via padded 32x32 LDS tiles. 128 blocks x 256.
__global__ void __launch_bounds__(256)
k_tr(const float* __restrict__ Qp, const float* __restrict__ Wq,
     float* __restrict__ ws) {
  __shared__ float tile[32][33];
  int bid = blockIdx.x, t = threadIdx.x;
  const float* src; float* dst; int ti;
  if (bid < 64) { src = Qp + 65536; dst = ws + WS_QPT; ti = bid; }
  else          { src = Wq;         dst = ws + WS_WQT; ti = bid - 64; }
  int tr = ti >> 3, tc = ti & 7;        // row-tile (j/d), col-tile (e)
  int c = t & 31, r0 = t >> 5;
  #pragma unroll
  for (int k = 0; k < 4; ++k) {         // load src tile, coalesced
    int r = r0 + (k << 3);
    tile[r][c] = src[(size_t)(tr * 32 + r) * 256 + tc * 32 + c];
  }
  __syncthreads();
  #pragma unroll
  for (int k = 0; k < 4; ++k) {         // store transposed, coalesced
    int r = r0 + (k << 3);
    dst[(size_t)(tc * 32 + r) * 256 + tr * 32 + c] = tile[c][r];
  }
}

// ---------------------------------------------------------------------------
// K1 prologue: QwT (64 blocks x 4 d-rows), Pq (32). 96 blocks x 256.
// QwT: stage 4 Wq rows in LDS, stream QPT once, 4 FMAs per load.
// Pq:  analytic pe in LDS, stream WqT. No syncs inside the loops.
__global__ void __launch_bounds__(256)
k_pro(const float* __restrict__ Wq, float* __restrict__ ws) {
  int bid = blockIdx.x, t = threadIdx.x;
  if (bid < 64) {                       // QwT[d0+r][j] = sum_e Wq[d0+r][e]*QpT[e][j]
    __shared__ float lvec[4][256];
    int d0 = bid << 2;
    #pragma unroll
    for (int r = 0; r < 4; ++r)
      lvec[r][t] = Wq[(size_t)(d0 + r) * 256 + t];
    __syncthreads();
    float acc0 = 0.f, acc1 = 0.f, acc2 = 0.f, acc3 = 0.f;
    const float* __restrict__ GT = ws + WS_QPT + t;
    #pragma unroll 8
    for (int e = 0; e < 256; ++e) {
      float q = GT[e << 8];             // coalesced; lvec broadcast
      acc0 += lvec[0][e] * q;
      acc1 += lvec[1][e] * q;
      acc2 += lvec[2][e] * q;
      acc3 += lvec[3][e] * q;
    }
    float* dst = ws + WS_QWT + (size_t)d0 * 256 + t;
    dst[0]   = acc0;
    dst[256] = acc1;
    dst[512] = acc2;
    dst[768] = acc3;
  } else {                              // Pq[b][d] = sum_e pe[b][e]*WqT[e][d]
    __shared__ float lvec[256];
    int b = bid - 64;
    int k2 = t & ~1;                    // arange value 2k
    float div = expf((float)k2 * (-9.210340371976184f / 256.f));
    float a = (float)b * div;
    lvec[t] = (t & 1) ? cosf(a) : sinf(a);
    __syncthreads();
    float acc = 0.f;
    const float* __restrict__ GT = ws + WS_WQT + t;
    #pragma unroll 8
    for (int e = 0; e < 256; ++e)
      acc += lvec[e] * GT[e << 8];
    ws[WS_PQ + b * 256 + t] = acc;
  }
}

// ---------------------------------------------------------------------------
// K2: U[h][e][j] and V[b][h][e].  512 blocks x 256.
//   [0,256):   U, (h, e-tile8): Wk tile staged in LDS (broadcast reads),
//              QwT streamed coalesced, 8 FMAs per load.
//   [256,512): V, (b,h): unchanged math.
__global__ void __launch_bounds__(256)
k_uv(const float* __restrict__ Wk, const float* __restrict__ bq,
     float* __restrict__ ws) {
  int bid = blockIdx.x, t = threadIdx.x;
  if (bid < 256) {
    int h = bid >> 5, e0 = (bid & 31) << 3;
    __shared__ float wk_s[32][9];       // [d in h][e0..e0+7], +1 pad
    {
      int d = t >> 3, i = t & 7;        // 256 threads cover 32x8
      wk_s[d][i] = Wk[(size_t)(h * 32 + d) * 256 + e0 + i];
    }
    __syncthreads();
    float acc[8] = {0.f, 0.f, 0.f, 0.f, 0.f, 0.f, 0.f, 0.f};
    const float* __restrict__ Qw = ws + WS_QWT + t;
    #pragma unroll 4
    for (int d = 0; d < 32; ++d) {
      float q = Qw[((h << 5) + d) << 8];  // coalesced; wk_s broadcast
      #pragma unroll
      for (int i = 0; i < 8; ++i) acc[i] += wk_s[d][i] * q;
    }
    float* Uh = ws + WS_U + (h << 16) + (size_t)e0 * 256;
    #pragma unroll
    for (int i = 0; i < 8; ++i) Uh[(size_t)i * 256 + t] = acc[i];
  } else {
    int idx = bid - 256, b = idx >> 3, h = idx & 7;
    float acc = 0.f;
#pragma unroll 8
    for (int dd = 0; dd < 32; ++dd) {
      int d = h * 32 + dd;
      acc += (ws[WS_PQ + b * 256 + d] + bq[d]) * Wk[(size_t)d * 256 + t];
    }
    ws[WS_V + ((b << 3) + h) * 256 + t] = acc;
  }
}

// ---------------------------------------------------------------------------
// K3: delta. 256 blocks = (b, j-tile of 32) x 256 threads. (unchanged)
__global__ void __launch_bounds__(256)
k_delta(const float* __restrict__ state, const float* __restrict__ obs,
        float* __restrict__ ws) {
  int b = blockIdx.x >> 3, jt = (blockIdx.x & 7) << 5;
  int t = threadIdx.x;
  __shared__ float Xs[256][33];         // X[e][j], +1 pad -> <=2-way (free)
  __shared__ float Vs[2048];            // V[b][h][e] slice
  __shared__ float pd[8][8][32];        // [eg][h][j] partial sum X*w
  __shared__ float pw[8][8][32];        // [eg][h][j] partial sum w
  __shared__ float px[8][32];           // [eg][j]    partial sum X (reused)
  {                                     // stage: (es 0..31, jq 0..7) float4
    int es = t >> 3, jq = t & 7;
    const float* sp = state + (size_t)b * 131072 + 256 + jt + (jq << 2);
    const float* op = obs   + (size_t)b * 65536  + jt + (jq << 2);
    #pragma unroll
    for (int k = 0; k < 8; ++k) {
      int e = es + (k << 5);
      float4 s4 = *(const float4*)(sp + (size_t)e * 512);
      float4 o4 = *(const float4*)(op + (size_t)e * 256);
      float* xr = &Xs[e][jq << 2];
      xr[0] = s4.x - o4.x; xr[1] = s4.y - o4.y;
      xr[2] = s4.z - o4.z; xr[3] = s4.w - o4.w;
    }
    for (int i = t; i < 2048; i += 256) Vs[i] = ws[WS_V + (b << 11) + i];
  }
  __syncthreads();
  int j = t & 31, eg = t >> 5, e0 = eg << 5;
  {                                     // a_x partial (h-independent)
    float ax = 0.f;
    #pragma unroll
    for (int ei = 0; ei < 32; ++ei) ax += Xs[e0 + ei][j];
    px[eg][j] = ax;
  }
  const float* __restrict__ Ub = ws + WS_U + jt + j;
  #pragma unroll
  for (int h = 0; h < 8; ++h) {
    float dacc = 0.f, wacc = 0.f;
    const float* __restrict__ Uh = Ub + (h << 16) + (e0 << 8);
    const float* __restrict__ Vh = Vs + (h << 8) + e0;
    #pragma unroll 16
    for (int ei = 0; ei < 32; ++ei) {
      float w = Uh[ei << 8] + Vh[ei];
      dacc += Xs[e0 + ei][j] * w;
      wacc += w;
    }
    pd[eg][h][j] = dacc;
    pw[eg][h][j] = wacc;
  }
  __syncthreads();
  int h2 = t >> 5, j2 = t & 31;         // thread -> (h, j) for the merge
  float D = 0.f, W = 0.f, X = 0.f;
  #pragma unroll
  for (int g = 0; g < 8; ++g) {
    D += pd[g][h2][j2];
    W += pw[g][h2][j2];
    X += px[g][j2];
  }
  float delta = D - X * (1.f / 256.f) * W;
  float sig = 1.f / (1.f + __expf(-delta * 0.17677669529663687f)); // /sqrt(32)
  __syncthreads();
  px[h2][j2] = sig;                     // reuse px as [h][j] sigmoid buffer
  __syncthreads();
  if (t < 32) {
    float acc = 0.f;
    #pragma unroll
    for (int h = 0; h < 8; ++h) acc += px[h][t];
    ws[WS_P + (b << 8) + jt + t] = acc; // sum_h; k_out applies *0.125
  }
}

// ---------------------------------------------------------------------------
// K4 fused output. 16384 blocks: [0,4096) new_state (2 rows/block, float4);
// rest atten float4s. All output stores nontemporal (write-once stream).
__global__ void __launch_bounds__(256)
k_out(const float* __restrict__ state, const float* __restrict__ obs,
      const float* __restrict__ ws, float* __restrict__ out) {
  int bid = blockIdx.x, t = threadIdx.x;
  if (bid < 4096) {                     // new_state rows, float4/thread
    int row = (bid << 1) | (t >> 7);    // row = b*256 + e
    int tt = t & 127;                   // cols l = 4tt..4tt+3
    int b = row >> 8;
    float4 sv = ((const float4*)(state + (size_t)row * 512))[tt];
    float* wrow = out + (size_t)row * 512 + (tt << 2);
    if (tt < 64) {
      nt_store4(wrow, sv.x, sv.y, sv.z, sv.w);  // l < 256: identity
    } else {
      float4 ov = ((const float4*)(obs + (size_t)row * 256))[tt - 64];
      float4 p4 = ((const float4*)(ws + WS_P + b * 256))[tt - 64];
      p4.x *= 0.125f; p4.y *= 0.125f; p4.z *= 0.125f; p4.w *= 0.125f;
      nt_store4(wrow,
                p4.x * sv.x + (1.f - p4.x) * ov.x,
                p4.y * sv.y + (1.f - p4.y) * ov.y,
                p4.z * sv.z + (1.f - p4.z) * ov.z,
                p4.w * sv.w + (1.f - p4.w) * ov.w);
    }
  } else {                              // atten, one float4 per thread
    int g4 = (bid - 4096) * 256 + t;    // 0..3145727
    int r = g4 / 192, c = g4 - r * 192; // r = b*512 + l
    int b = r >> 9, l = r & 511;
    int s0 = c << 2;
    float v[4] = {0.f, 0.f, 0.f, 0.f};
    if (l < 256) {
      if (l >= s0 && l < s0 + 4) v[l - s0] = 1.0f;
    } else {
      float p = ws[WS_P + b * 256 + (l - 256)] * 0.125f;
      if (l >= s0 && l < s0 + 4) v[l - s0] = p;
      int s2 = l + 256;
      if (s2 >= s0 && s2 < s0 + 4) v[s2 - s0] = 1.0f - p;
    }
    nt_store4(out + 4194304 + ((size_t)g4 << 2), v[0], v[1], v[2], v[3]);
  }
}

extern "C" void kernel_launch(void* const* d_in, const int* in_sizes, int n_in,
                              void* d_out, int out_size, void* d_ws, size_t ws_size,
                              hipStream_t stream) {
  const float *state = nullptr, *obs = nullptr, *Qp = nullptr;
  const float *Wq = nullptr, *Wk = nullptr, *bq = nullptr, *bk = nullptr;
  for (int i = 0; i < n_in; ++i) {
    int s = in_sizes[i];
    const float* p = (const float*)d_in[i];
    if      (s == 4194304) state = p;
    else if (s == 2097152) obs = p;
    else if (s == 131072)  Qp = p;
    else if (s == 65536)   { if (!Wq) Wq = p; else Wk = p; }
    else if (s == 256)     { if (!bq) bq = p; else bk = p; }
  }
  (void)bk;                             // cancels in the 2-way softmax
  float* out = (float*)d_out;
  float* ws  = (float*)d_ws;

  k_tr   <<<128,   256, 0, stream>>>(Qp, Wq, ws);
  k_pro  <<<96,    256, 0, stream>>>(Wq, ws);
  k_uv   <<<512,   256, 0, stream>>>(Wk, bq, ws);
  k_delta<<<256,   256, 0, stream>>>(state, obs, ws);
  k_out  <<<16384, 256, 0, stream>>>(state, obs, ws, out);
}

// Round 10
// 125.086 us; speedup vs baseline: 2.9517x; 1.0236x over previous
//
#include <hip/hip_runtime.h>
#include <stdint.h>
#include <math.h>

// Validated semantics (r17/r18 green): printed reference, fp32 in/out.
//   p[b,j] = mean_h sigmoid(delta/sqrt(32)),
//   delta[j,b,h] = sum_e D_e*(U+V),  D_e = (s_e-mu_s)-(o_e-mu_o)
//   Folded mu: sum_e D*w = sum_e (s-o)*w - ((sum s - sum o)/256)*sum_e w
//   U[h,e,j] = sum_{d in h} QwT[d,j]*Wk[d,e],  QwT = Qp[256+j]@Wq^T
//   V[b,h,e] = sum_{d in h} (Pq[b,d]+bq[d])*Wk[d,e],  Pq = pe[b]@Wq^T
//   new_state[b,e,l<256]=state; l>=256: p*s_l+(1-p)*o_{l-256} = o + p*(s-o)
//   atten[b,l,s]: l<256 -> 1 at s=l; else p at s=l, 1-p at s=l+256.
// r9 post-mortem: 96-block k_pro starved the chip (<256 CUs) -> reverted to
// r6's 288-block k_pro. This round: fuse the new_state MERGE half into
// k_delta's epilogue (it already holds X=s-o in LDS and loads exactly the
// needed state/obs columns) -> k_out loses 17 MB of reads; k_out = identity
// copy + atten only. Everything else byte-identical to the 126.56us r6 build.

// d_ws layout (floats) — unchanged
#define WS_P    0        // [32 b][256 j]  sum_h sigmoid
#define WS_QWT  8192     // [256 d][256 j]
#define WS_PQ   73728    // [32 b][256 d]
#define WS_U    81920    // [8 h][256 e][256 j]
#define WS_V    606208   // [32 b][8 h][256 e]
#define WS_QPT  671744   // [256 e][256 j]  QpT[e][j] = Qp[256+j][e]
#define WS_WQT  737280   // [256 e][256 d]  WqT[e][d] = Wq[d][e]
// end 802816 floats = 3.06 MB (ws is 256 MiB per fill WRITE_SIZE)

typedef float vf4 __attribute__((ext_vector_type(4)));
__device__ __forceinline__ void nt_store4(float* p, float x, float y,
                                          float z, float w) {
  vf4 v; v.x = x; v.y = y; v.z = z; v.w = w;
  __builtin_nontemporal_store(v, (vf4*)p);
}

// ---------------------------------------------------------------------------
// K0 transpose: QpT and WqT via padded 32x32 LDS tiles. 128 blocks x 256.
__global__ void __launch_bounds__(256)
k_tr(const float* __restrict__ Qp, const float* __restrict__ Wq,
     float* __restrict__ ws) {
  __shared__ float tile[32][33];
  int bid = blockIdx.x, t = threadIdx.x;
  const float* src; float* dst; int ti;
  if (bid < 64) { src = Qp + 65536; dst = ws + WS_QPT; ti = bid; }
  else          { src = Wq;         dst = ws + WS_WQT; ti = bid - 64; }
  int tr = ti >> 3, tc = ti & 7;        // row-tile (j/d), col-tile (e)
  int c = t & 31, r0 = t >> 5;
  #pragma unroll
  for (int k = 0; k < 4; ++k) {         // load src tile, coalesced
    int r = r0 + (k << 3);
    tile[r][c] = src[(size_t)(tr * 32 + r) * 256 + tc * 32 + c];
  }
  __syncthreads();
  #pragma unroll
  for (int k = 0; k < 4; ++k) {         // store transposed, coalesced
    int r = r0 + (k << 3);
    dst[(size_t)(tc * 32 + r) * 256 + tr * 32 + c] = tile[c][r];
  }
}

// ---------------------------------------------------------------------------
// K1 prologue: QwT (256 blocks), Pq (32). 288 blocks x 256.  (r6 version)
__global__ void __launch_bounds__(256)
k_pro(const float* __restrict__ Wq, float* __restrict__ ws) {
  int bid = blockIdx.x, t = threadIdx.x;
  __shared__ float lvec[256];
  const float* __restrict__ GT; float* dst;
  if (bid < 256) {                      // QwT[d][j] = sum_e Wq[d][e]*QpT[e][j]
    int d = bid;
    lvec[t] = Wq[(size_t)d * 256 + t];
    GT = ws + WS_QPT; dst = ws + WS_QWT + d * 256;
  } else {                              // Pq[b][d] = sum_e pe[b][e]*WqT[e][d]
    int b = bid - 256;
    int k2 = t & ~1;                    // arange value 2k
    float div = expf((float)k2 * (-9.210340371976184f / 256.f));
    float a = (float)b * div;
    lvec[t] = (t & 1) ? cosf(a) : sinf(a);
    GT = ws + WS_WQT; dst = ws + WS_PQ + b * 256;
  }
  __syncthreads();
  float acc = 0.f;
  #pragma unroll 8
  for (int e = 0; e < 256; ++e)
    acc += lvec[e] * GT[(e << 8) + t];
  dst[t] = acc;
}

// ---------------------------------------------------------------------------
// K2: U[h][e][j] and V[b][h][e].  512 blocks x 256.  (r6 version)
__global__ void __launch_bounds__(256)
k_uv(const float* __restrict__ Wk, const float* __restrict__ bq,
     float* __restrict__ ws) {
  int bid = blockIdx.x, t = threadIdx.x;
  if (bid < 256) {
    int h = bid >> 5, e0 = (bid & 31) << 3;
    __shared__ float wk_s[32][9];       // [d in h][e0..e0+7], +1 pad
    {
      int d = t >> 3, i = t & 7;        // 256 threads cover 32x8
      wk_s[d][i] = Wk[(size_t)(h * 32 + d) * 256 + e0 + i];
    }
    __syncthreads();
    float acc[8] = {0.f, 0.f, 0.f, 0.f, 0.f, 0.f, 0.f, 0.f};
    const float* __restrict__ Qw = ws + WS_QWT + t;
    #pragma unroll 4
    for (int d = 0; d < 32; ++d) {
      float q = Qw[((h << 5) + d) << 8];  // coalesced; wk_s broadcast
      #pragma unroll
      for (int i = 0; i < 8; ++i) acc[i] += wk_s[d][i] * q;
    }
    float* Uh = ws + WS_U + (h << 16) + (size_t)e0 * 256;
    #pragma unroll
    for (int i = 0; i < 8; ++i) Uh[(size_t)i * 256 + t] = acc[i];
  } else {
    int idx = bid - 256, b = idx >> 3, h = idx & 7;
    float acc = 0.f;
#pragma unroll 8
    for (int dd = 0; dd < 32; ++dd) {
      int d = h * 32 + dd;
      acc += (ws[WS_PQ + b * 256 + d] + bq[d]) * Wk[(size_t)d * 256 + t];
    }
    ws[WS_V + ((b << 3) + h) * 256 + t] = acc;
  }
}

// ---------------------------------------------------------------------------
// K3: delta + fused merge-columns write. 256 blocks = (b, j-tile32) x 256.
// Same delta math as r6; epilogue writes new_state[b, :, 256+jt..256+jt+31]
// = obs + p*X using the already-staged X and a broadcast p (LDS).
__global__ void __launch_bounds__(256)
k_delta(const float* __restrict__ state, const float* __restrict__ obs,
        float* __restrict__ ws, float* __restrict__ out) {
  int b = blockIdx.x >> 3, jt = (blockIdx.x & 7) << 5;
  int t = threadIdx.x;
  __shared__ float Xs[256][33];         // X[e][j], +1 pad -> <=2-way (free)
  __shared__ float Vs[2048];            // V[b][h][e] slice
  __shared__ float pd[8][8][32];        // [eg][h][j] partial sum X*w
  __shared__ float pw[8][8][32];        // [eg][h][j] partial sum w
  __shared__ float px[8][32];           // [eg][j]    partial sum X (reused)
  __shared__ float pfin[32];            // final p[b, jt+j] (mean_h * 0.125)
  {                                     // stage: (es 0..31, jq 0..7) float4
    int es = t >> 3, jq = t & 7;
    const float* sp = state + (size_t)b * 131072 + 256 + jt + (jq << 2);
    const float* op = obs   + (size_t)b * 65536  + jt + (jq << 2);
    #pragma unroll
    for (int k = 0; k < 8; ++k) {
      int e = es + (k << 5);
      float4 s4 = *(const float4*)(sp + (size_t)e * 512);
      float4 o4 = *(const float4*)(op + (size_t)e * 256);
      float* xr = &Xs[e][jq << 2];
      xr[0] = s4.x - o4.x; xr[1] = s4.y - o4.y;
      xr[2] = s4.z - o4.z; xr[3] = s4.w - o4.w;
    }
    for (int i = t; i < 2048; i += 256) Vs[i] = ws[WS_V + (b << 11) + i];
  }
  __syncthreads();
  int j = t & 31, eg = t >> 5, e0 = eg << 5;
  {                                     // a_x partial (h-independent)
    float ax = 0.f;
    #pragma unroll
    for (int ei = 0; ei < 32; ++ei) ax += Xs[e0 + ei][j];
    px[eg][j] = ax;
  }
  const float* __restrict__ Ub = ws + WS_U + jt + j;
  #pragma unroll
  for (int h = 0; h < 8; ++h) {
    float dacc = 0.f, wacc = 0.f;
    const float* __restrict__ Uh = Ub + (h << 16) + (e0 << 8);
    const float* __restrict__ Vh = Vs + (h << 8) + e0;
    #pragma unroll 16
    for (int ei = 0; ei < 32; ++ei) {
      float w = Uh[ei << 8] + Vh[ei];
      dacc += Xs[e0 + ei][j] * w;
      wacc += w;
    }
    pd[eg][h][j] = dacc;
    pw[eg][h][j] = wacc;
  }
  __syncthreads();
  int h2 = t >> 5, j2 = t & 31;         // thread -> (h, j) for the merge
  float D = 0.f, W = 0.f, X = 0.f;
  #pragma unroll
  for (int g = 0; g < 8; ++g) {
    D += pd[g][h2][j2];
    W += pw[g][h2][j2];
    X += px[g][j2];
  }
  float delta = D - X * (1.f / 256.f) * W;
  float sig = 1.f / (1.f + __expf(-delta * 0.17677669529663687f)); // /sqrt(32)
  __syncthreads();
  px[h2][j2] = sig;                     // reuse px as [h][j] sigmoid buffer
  __syncthreads();
  if (t < 32) {
    float acc = 0.f;
    #pragma unroll
    for (int h = 0; h < 8; ++h) acc += px[h][t];
    ws[WS_P + (b << 8) + jt + t] = acc; // sum_h; k_out atten applies *0.125
    pfin[t] = acc * 0.125f;             // p for the fused merge
  }
  __syncthreads();
  // Fused merge: new_state[b, e, 256+jt+j] = o + p*X. Thread t -> e-rows
  // (t>>3)+32k, j-quad (t&7)*4. obs re-read is L2-hot (just staged).
  {
    int eb = t >> 3, j0 = (t & 7) << 2;
    const float* op2 = obs + (size_t)b * 65536 + jt + j0;
    float p0 = pfin[j0], p1 = pfin[j0 + 1], p2 = pfin[j0 + 2], p3 = pfin[j0 + 3];
    float* orow = out + (size_t)b * 131072 + 256 + jt + j0;
    #pragma unroll
    for (int k = 0; k < 8; ++k) {
      int e = eb + (k << 5);
      float4 o4 = *(const float4*)(op2 + (size_t)e * 256);
      const float* xr = &Xs[e][j0];
      nt_store4(orow + (size_t)e * 512,
                o4.x + p0 * xr[0], o4.y + p1 * xr[1],
                o4.z + p2 * xr[2], o4.w + p3 * xr[3]);
    }
  }
}

// ---------------------------------------------------------------------------
// K4 output. 14336 blocks: [0,2048) new_state identity half (4 rows/block,
// lower 64 f4 each); [2048,14336) atten float4s (r6 path, unchanged).
__global__ void __launch_bounds__(256)
k_out(const float* __restrict__ state, const float* __restrict__ ws,
      float* __restrict__ out) {
  int bid = blockIdx.x, t = threadIdx.x;
  if (bid < 2048) {                     // new_state[b,e,0..255] = state
    int row = (bid << 2) | (t >> 6);    // row = b*256 + e
    int c = t & 63;                     // f4 col in lower half
    float4 sv = ((const float4*)(state + (size_t)row * 512))[c];
    nt_store4(out + (size_t)row * 512 + (c << 2), sv.x, sv.y, sv.z, sv.w);
  } else {                              // atten, one float4 per thread
    int g4 = (bid - 2048) * 256 + t;    // 0..3145727
    int r = g4 / 192, c = g4 - r * 192; // r = b*512 + l
    int b = r >> 9, l = r & 511;
    int s0 = c << 2;
    float v[4] = {0.f, 0.f, 0.f, 0.f};
    if (l < 256) {
      if (l >= s0 && l < s0 + 4) v[l - s0] = 1.0f;
    } else {
      float p = ws[WS_P + b * 256 + (l - 256)] * 0.125f;
      if (l >= s0 && l < s0 + 4) v[l - s0] = p;
      int s2 = l + 256;
      if (s2 >= s0 && s2 < s0 + 4) v[s2 - s0] = 1.0f - p;
    }
    nt_store4(out + 4194304 + ((size_t)g4 << 2), v[0], v[1], v[2], v[3]);
  }
}

extern "C" void kernel_launch(void* const* d_in, const int* in_sizes, int n_in,
                              void* d_out, int out_size, void* d_ws, size_t ws_size,
                              hipStream_t stream) {
  const float *state = nullptr, *obs = nullptr, *Qp = nullptr;
  const float *Wq = nullptr, *Wk = nullptr, *bq = nullptr, *bk = nullptr;
  for (int i = 0; i < n_in; ++i) {
    int s = in_sizes[i];
    const float* p = (const float*)d_in[i];
    if      (s == 4194304) state = p;
    else if (s == 2097152) obs = p;
    else if (s == 131072)  Qp = p;
    else if (s == 65536)   { if (!Wq) Wq = p; else Wk = p; }
    else if (s == 256)     { if (!bq) bq = p; else bk = p; }
  }
  (void)bk;                             // cancels in the 2-way softmax
  float* out = (float*)d_out;
  float* ws  = (float*)d_ws;

  k_tr   <<<128,   256, 0, stream>>>(Qp, Wq, ws);
  k_pro  <<<288,   256, 0, stream>>>(Wq, ws);
  k_uv   <<<512,   256, 0, stream>>>(Wk, bq, ws);
  k_delta<<<256,   256, 0, stream>>>(state, obs, ws, out);
  k_out  <<<14336, 256, 0, stream>>>(state, ws, out);
}

// Round 11
// 123.677 us; speedup vs baseline: 2.9853x; 1.0114x over previous
//
#include <hip/hip_runtime.h>
#include <stdint.h>
#include <math.h>

// Validated semantics (r17/r18 green): printed reference, fp32 in/out.
//   p[b,j] = mean_h sigmoid(delta/sqrt(32)),
//   delta[j,b,h] = sum_e D_e*(U+V),  D_e = (s_e-mu_s)-(o_e-mu_o)
//   Folded mu: sum_e D*w = sum_e (s-o)*w - ((sum s - sum o)/256)*sum_e w
//   U[h,e,j] = sum_{d in h} QwT[d,j]*Wk[d,e],  QwT = Qp[256+j]@Wq^T
//   V[b,h,e] = sum_{d in h} (Pq[b,d]+bq[d])*Wk[d,e],  Pq = pe[b]@Wq^T
//   new_state[b,e,l<256]=state; l>=256: p*s_l+(1-p)*o_{l-256} = o + p*(s-o)
//   atten[b,l,s]: l<256 -> 1 at s=l; else p at s=l, 1-p at s=l+256.
// This round: delete the k_out launch. Each delta block locally owns
// P[b, jt..jt+31] = the diag of atten rows l=256+jt+j, so it writes those
// two float4s itself; all remaining output is P-independent and its blocks
// are absorbed into k_delta's grid (256 delta + 2048 identity + 12288 atten
// = 14592 blocks). Static atten writers skip the 2 diag f4s per l>=256 row
// (disjoint addresses, no race). 5 launches -> 4; 59 MB of static writes
// overlap delta's compute. k_tr/k_pro/k_uv byte-identical to r10 (125.1us).

// d_ws layout (floats) — unchanged
#define WS_P    0        // [32 b][256 j]  sum_h sigmoid
#define WS_QWT  8192     // [256 d][256 j]
#define WS_PQ   73728    // [32 b][256 d]
#define WS_U    81920    // [8 h][256 e][256 j]
#define WS_V    606208   // [32 b][8 h][256 e]
#define WS_QPT  671744   // [256 e][256 j]  QpT[e][j] = Qp[256+j][e]
#define WS_WQT  737280   // [256 e][256 d]  WqT[e][d] = Wq[d][e]
// end 802816 floats = 3.06 MB (ws is 256 MiB per fill WRITE_SIZE)

typedef float vf4 __attribute__((ext_vector_type(4)));
__device__ __forceinline__ void nt_store4(float* p, float x, float y,
                                          float z, float w) {
  vf4 v; v.x = x; v.y = y; v.z = z; v.w = w;
  __builtin_nontemporal_store(v, (vf4*)p);
}

// ---------------------------------------------------------------------------
// K0 transpose: QpT and WqT via padded 32x32 LDS tiles. 128 blocks x 256.
__global__ void __launch_bounds__(256)
k_tr(const float* __restrict__ Qp, const float* __restrict__ Wq,
     float* __restrict__ ws) {
  __shared__ float tile[32][33];
  int bid = blockIdx.x, t = threadIdx.x;
  const float* src; float* dst; int ti;
  if (bid < 64) { src = Qp + 65536; dst = ws + WS_QPT; ti = bid; }
  else          { src = Wq;         dst = ws + WS_WQT; ti = bid - 64; }
  int tr = ti >> 3, tc = ti & 7;        // row-tile (j/d), col-tile (e)
  int c = t & 31, r0 = t >> 5;
  #pragma unroll
  for (int k = 0; k < 4; ++k) {         // load src tile, coalesced
    int r = r0 + (k << 3);
    tile[r][c] = src[(size_t)(tr * 32 + r) * 256 + tc * 32 + c];
  }
  __syncthreads();
  #pragma unroll
  for (int k = 0; k < 4; ++k) {         // store transposed, coalesced
    int r = r0 + (k << 3);
    dst[(size_t)(tc * 32 + r) * 256 + tr * 32 + c] = tile[c][r];
  }
}

// ---------------------------------------------------------------------------
// K1 prologue: QwT (256 blocks), Pq (32). 288 blocks x 256.  (r6 version)
__global__ void __launch_bounds__(256)
k_pro(const float* __restrict__ Wq, float* __restrict__ ws) {
  int bid = blockIdx.x, t = threadIdx.x;
  __shared__ float lvec[256];
  const float* __restrict__ GT; float* dst;
  if (bid < 256) {                      // QwT[d][j] = sum_e Wq[d][e]*QpT[e][j]
    int d = bid;
    lvec[t] = Wq[(size_t)d * 256 + t];
    GT = ws + WS_QPT; dst = ws + WS_QWT + d * 256;
  } else {                              // Pq[b][d] = sum_e pe[b][e]*WqT[e][d]
    int b = bid - 256;
    int k2 = t & ~1;                    // arange value 2k
    float div = expf((float)k2 * (-9.210340371976184f / 256.f));
    float a = (float)b * div;
    lvec[t] = (t & 1) ? cosf(a) : sinf(a);
    GT = ws + WS_WQT; dst = ws + WS_PQ + b * 256;
  }
  __syncthreads();
  float acc = 0.f;
  #pragma unroll 8
  for (int e = 0; e < 256; ++e)
    acc += lvec[e] * GT[(e << 8) + t];
  dst[t] = acc;
}

// ---------------------------------------------------------------------------
// K2: U[h][e][j] and V[b][h][e].  512 blocks x 256.  (r6 version)
__global__ void __launch_bounds__(256)
k_uv(const float* __restrict__ Wk, const float* __restrict__ bq,
     float* __restrict__ ws) {
  int bid = blockIdx.x, t = threadIdx.x;
  if (bid < 256) {
    int h = bid >> 5, e0 = (bid & 31) << 3;
    __shared__ float wk_s[32][9];       // [d in h][e0..e0+7], +1 pad
    {
      int d = t >> 3, i = t & 7;        // 256 threads cover 32x8
      wk_s[d][i] = Wk[(size_t)(h * 32 + d) * 256 + e0 + i];
    }
    __syncthreads();
    float acc[8] = {0.f, 0.f, 0.f, 0.f, 0.f, 0.f, 0.f, 0.f};
    const float* __restrict__ Qw = ws + WS_QWT + t;
    #pragma unroll 4
    for (int d = 0; d < 32; ++d) {
      float q = Qw[((h << 5) + d) << 8];  // coalesced; wk_s broadcast
      #pragma unroll
      for (int i = 0; i < 8; ++i) acc[i] += wk_s[d][i] * q;
    }
    float* Uh = ws + WS_U + (h << 16) + (size_t)e0 * 256;
    #pragma unroll
    for (int i = 0; i < 8; ++i) Uh[(size_t)i * 256 + t] = acc[i];
  } else {
    int idx = bid - 256, b = idx >> 3, h = idx & 7;
    float acc = 0.f;
#pragma unroll 8
    for (int dd = 0; dd < 32; ++dd) {
      int d = h * 32 + dd;
      acc += (ws[WS_PQ + b * 256 + d] + bq[d]) * Wk[(size_t)d * 256 + t];
    }
    ws[WS_V + ((b << 3) + h) * 256 + t] = acc;
  }
}

// ---------------------------------------------------------------------------
// K3: delta + ALL output. 14592 blocks x 256.
//   [0,256):        delta compute (b, j-tile32) + merge cols + atten diag
//   [256,2304):     new_state identity half (state cols 0..255)
//   [2304,14592):   atten static (one-hot l<256; zeros l>=256 minus diag f4s)
__global__ void __launch_bounds__(256)
k_delta(const float* __restrict__ state, const float* __restrict__ obs,
        float* __restrict__ ws, float* __restrict__ out) {
  int bid = blockIdx.x, t = threadIdx.x;
  if (bid < 256) {
    int b = bid >> 3, jt = (bid & 7) << 5;
    __shared__ float Xs[256][33];       // X[e][j], +1 pad -> <=2-way (free)
    __shared__ float Vs[2048];          // V[b][h][e] slice
    __shared__ float pd[8][8][32];      // [eg][h][j] partial sum X*w
    __shared__ float pw[8][8][32];      // [eg][h][j] partial sum w
    __shared__ float px[8][32];         // [eg][j]    partial sum X (reused)
    __shared__ float pfin[32];          // final p[b, jt+j]
    {                                   // stage: (es 0..31, jq 0..7) float4
      int es = t >> 3, jq = t & 7;
      const float* sp = state + (size_t)b * 131072 + 256 + jt + (jq << 2);
      const float* op = obs   + (size_t)b * 65536  + jt + (jq << 2);
      #pragma unroll
      for (int k = 0; k < 8; ++k) {
        int e = es + (k << 5);
        float4 s4 = *(const float4*)(sp + (size_t)e * 512);
        float4 o4 = *(const float4*)(op + (size_t)e * 256);
        float* xr = &Xs[e][jq << 2];
        xr[0] = s4.x - o4.x; xr[1] = s4.y - o4.y;
        xr[2] = s4.z - o4.z; xr[3] = s4.w - o4.w;
      }
      for (int i = t; i < 2048; i += 256) Vs[i] = ws[WS_V + (b << 11) + i];
    }
    __syncthreads();
    int j = t & 31, eg = t >> 5, e0 = eg << 5;
    {                                   // a_x partial (h-independent)
      float ax = 0.f;
      #pragma unroll
      for (int ei = 0; ei < 32; ++ei) ax += Xs[e0 + ei][j];
      px[eg][j] = ax;
    }
    const float* __restrict__ Ub = ws + WS_U + jt + j;
    #pragma unroll
    for (int h = 0; h < 8; ++h) {
      float dacc = 0.f, wacc = 0.f;
      const float* __restrict__ Uh = Ub + (h << 16) + (e0 << 8);
      const float* __restrict__ Vh = Vs + (h << 8) + e0;
      #pragma unroll 16
      for (int ei = 0; ei < 32; ++ei) {
        float w = Uh[ei << 8] + Vh[ei];
        dacc += Xs[e0 + ei][j] * w;
        wacc += w;
      }
      pd[eg][h][j] = dacc;
      pw[eg][h][j] = wacc;
    }
    __syncthreads();
    int h2 = t >> 5, j2 = t & 31;       // thread -> (h, j) for the merge
    float D = 0.f, W = 0.f, X = 0.f;
    #pragma unroll
    for (int g = 0; g < 8; ++g) {
      D += pd[g][h2][j2];
      W += pw[g][h2][j2];
      X += px[g][j2];
    }
    float delta = D - X * (1.f / 256.f) * W;
    float sig = 1.f / (1.f + __expf(-delta * 0.17677669529663687f)); // /sqrt(32)
    __syncthreads();
    px[h2][j2] = sig;                   // reuse px as [h][j] sigmoid buffer
    __syncthreads();
    if (t < 32) {
      float acc = 0.f;
      #pragma unroll
      for (int h = 0; h < 8; ++h) acc += px[h][t];
      ws[WS_P + (b << 8) + jt + t] = acc;   // (kept for debug/consistency)
      float p = acc * 0.125f;
      pfin[t] = p;
      // atten diagonal: row l = 256+jt+t, f4 c1 = l>>2 (s=l), c2 = c1+64
      int l = 256 + jt + t;
      size_t rb = 4194304 + (size_t)((b << 9) + l) * 768;
      int c1 = l >> 2, pos = l & 3;
      float v1[4] = {0.f, 0.f, 0.f, 0.f}; v1[pos] = p;
      nt_store4(out + rb + (c1 << 2), v1[0], v1[1], v1[2], v1[3]);
      float v2[4] = {0.f, 0.f, 0.f, 0.f}; v2[pos] = 1.f - p;
      nt_store4(out + rb + ((c1 + 64) << 2), v2[0], v2[1], v2[2], v2[3]);
    }
    __syncthreads();
    // Fused merge: new_state[b, e, 256+jt+j] = o + p*X.
    {
      int eb = t >> 3, j0 = (t & 7) << 2;
      const float* op2 = obs + (size_t)b * 65536 + jt + j0;
      float p0 = pfin[j0], p1 = pfin[j0 + 1], p2 = pfin[j0 + 2], p3 = pfin[j0 + 3];
      float* orow = out + (size_t)b * 131072 + 256 + jt + j0;
      #pragma unroll
      for (int k = 0; k < 8; ++k) {
        int e = eb + (k << 5);
        float4 o4 = *(const float4*)(op2 + (size_t)e * 256);
        const float* xr = &Xs[e][j0];
        nt_store4(orow + (size_t)e * 512,
                  o4.x + p0 * xr[0], o4.y + p1 * xr[1],
                  o4.z + p2 * xr[2], o4.w + p3 * xr[3]);
      }
    }
  } else if (bid < 2304) {              // new_state[b,e,0..255] = state
    int row = ((bid - 256) << 2) | (t >> 6);  // row = b*256 + e
    int c = t & 63;                     // f4 col in lower half
    float4 sv = ((const float4*)(state + (size_t)row * 512))[c];
    nt_store4(out + (size_t)row * 512 + (c << 2), sv.x, sv.y, sv.z, sv.w);
  } else {                              // atten static, one float4 per thread
    int g4 = (bid - 2304) * 256 + t;    // 0..3145727
    int r = g4 / 192, c = g4 - r * 192; // r = b*512 + l
    int b = r >> 9, l = r & 511;
    int s0 = c << 2;
    if (l < 256) {                      // one-hot at s=l (P-independent)
      float v[4] = {0.f, 0.f, 0.f, 0.f};
      if (l >= s0 && l < s0 + 4) v[l - s0] = 1.0f;
      nt_store4(out + 4194304 + ((size_t)g4 << 2), v[0], v[1], v[2], v[3]);
    } else {                            // zeros, skipping the 2 diag f4s
      int c1 = l >> 2;                  // s=l f4 (64..127); c2 = c1+64
      if (c != c1 && c != c1 + 64)
        nt_store4(out + 4194304 + ((size_t)g4 << 2), 0.f, 0.f, 0.f, 0.f);
    }
  }
}

extern "C" void kernel_launch(void* const* d_in, const int* in_sizes, int n_in,
                              void* d_out, int out_size, void* d_ws, size_t ws_size,
                              hipStream_t stream) {
  const float *state = nullptr, *obs = nullptr, *Qp = nullptr;
  const float *Wq = nullptr, *Wk = nullptr, *bq = nullptr, *bk = nullptr;
  for (int i = 0; i < n_in; ++i) {
    int s = in_sizes[i];
    const float* p = (const float*)d_in[i];
    if      (s == 4194304) state = p;
    else if (s == 2097152) obs = p;
    else if (s == 131072)  Qp = p;
    else if (s == 65536)   { if (!Wq) Wq = p; else Wk = p; }
    else if (s == 256)     { if (!bq) bq = p; else bk = p; }
  }
  (void)bk;                             // cancels in the 2-way softmax
  float* out = (float*)d_out;
  float* ws  = (float*)d_ws;

  k_tr   <<<128,   256, 0, stream>>>(Qp, Wq, ws);
  k_pro  <<<288,   256, 0, stream>>>(Wq, ws);
  k_uv   <<<512,   256, 0, stream>>>(Wk, bq, ws);
  k_delta<<<14592, 256, 0, stream>>>(state, obs, ws, out);
}

// Round 12
// 117.994 us; speedup vs baseline: 3.1291x; 1.0482x over previous
//
#include <hip/hip_runtime.h>
#include <stdint.h>
#include <math.h>

// Validated semantics (r17/r18 green): printed reference, fp32 in/out.
//   p[b,j] = mean_h sigmoid(delta/sqrt(32)),
//   delta[j,b,h] = sum_e D_e*(U+V),  D_e = (s_e-mu_s)-(o_e-mu_o)
//   Folded mu: sum_e D*w = sum_e (s-o)*w - ((sum s - sum o)/256)*sum_e w
//   U[h,e,j] = sum_{d in h} QwT[d,j]*Wk[d,e],  QwT = Qp[256+j]@Wq^T
//   V[b,h,e] = sum_{d in h} (Pq[b,d]+bq[d])*Wk[d,e],  Pq = pe[b]@Wq^T
//   new_state[b,e,l<256]=state; l>=256: p*s_l+(1-p)*o_{l-256} = o + p*(s-o)
//   atten[b,l,s]: l<256 -> 1 at s=l; else p at s=l, 1-p at s=l+256.
// This round: k_tr+k_pro replaced by ONE kernel k_qw computing QwT and Pq
// directly from row-major Qp/Wq as A*B^T LDS-tile GEMMs (32x32 out tiles,
// e-chunked staging, f4 LDS reads, 4 acc/thread). No transpose stage, L2
// operand traffic 74->6 MB, 4 launches -> 3. k_uv/k_delta byte-identical to
// the 123.68us r11 build (dead ws[WS_P] store dropped — diag fused in r11).

// d_ws layout (floats) — unchanged (QPT/WQT regions now unused)
#define WS_P    0        // [32 b][256 j]  (unused since r11 diag fusion)
#define WS_QWT  8192     // [256 d][256 j]
#define WS_PQ   73728    // [32 b][256 d]
#define WS_U    81920    // [8 h][256 e][256 j]
#define WS_V    606208   // [32 b][8 h][256 e]

typedef float vf4 __attribute__((ext_vector_type(4)));
__device__ __forceinline__ void nt_store4(float* p, float x, float y,
                                          float z, float w) {
  vf4 v; v.x = x; v.y = y; v.z = z; v.w = w;
  __builtin_nontemporal_store(v, (vf4*)p);
}

// ---------------------------------------------------------------------------
// K1: QwT (64 tile-blocks) + Pq (8 tile-blocks). 72 blocks x 256.
//   QwT[d][j] = sum_e Wq[d][e]*Qp[256+j][e]  — 32d x 32j tile per block
//   Pq[b][d]  = sum_e pe[b][e]*Wq[d][e]      — 32b x 32d tile per block
// Row-tiles staged in LDS (e-chunks of 128, stride 132 keeps f4 16B-aligned);
// each thread owns 4 outputs; f4 LDS reads, accumulate across chunks.
__global__ void __launch_bounds__(256)
k_qw(const float* __restrict__ Qp, const float* __restrict__ Wq,
     float* __restrict__ ws) {
  int bid = blockIdx.x, t = threadIdx.x;
  if (bid < 64) {                       // QwT tile
    __shared__ float wq_s[32][132];
    __shared__ float qp_s[32][132];
    int d0 = (bid >> 3) << 5, j0 = (bid & 7) << 5;
    int j = t & 31, dq = t >> 5;        // thread: j, d = d0+dq*4..+3
    float acc[4] = {0.f, 0.f, 0.f, 0.f};
    for (int ec = 0; ec < 256; ec += 128) {
      #pragma unroll
      for (int k = 0; k < 4; ++k) {     // stage both tiles, f4 coalesced
        int i = (k << 8) + t;           // 0..1023
        int r = i >> 5, c4 = i & 31;    // row, f4-col of 128-float chunk
        *(float4*)&wq_s[r][c4 << 2] =
            *(const float4*)(Wq + (size_t)(d0 + r) * 256 + ec + (c4 << 2));
        *(float4*)&qp_s[r][c4 << 2] =
            *(const float4*)(Qp + 65536 + (size_t)(j0 + r) * 256 + ec + (c4 << 2));
      }
      __syncthreads();
      #pragma unroll 8
      for (int e4 = 0; e4 < 32; ++e4) {
        float4 q = *(const float4*)&qp_s[j][e4 << 2];
        #pragma unroll
        for (int r = 0; r < 4; ++r) {
          float4 w = *(const float4*)&wq_s[(dq << 2) + r][e4 << 2];
          acc[r] += w.x * q.x + w.y * q.y + w.z * q.z + w.w * q.w;
        }
      }
      __syncthreads();
    }
    #pragma unroll
    for (int r = 0; r < 4; ++r)         // lanes j consecutive -> coalesced
      ws[WS_QWT + (size_t)(d0 + (dq << 2) + r) * 256 + j0 + j] = acc[r];
  } else {                              // Pq tile
    __shared__ float wq_s[32][132];
    __shared__ float pe_s[32][132];
    int d0 = (bid - 64) << 5;
    int b = t & 31, dq = t >> 5;        // thread: b, d = d0+dq*4..+3
    float acc[4] = {0.f, 0.f, 0.f, 0.f};
    for (int ec = 0; ec < 256; ec += 128) {
      #pragma unroll
      for (int k = 0; k < 4; ++k) {     // stage Wq tile
        int i = (k << 8) + t;
        int r = i >> 5, c4 = i & 31;
        *(float4*)&wq_s[r][c4 << 2] =
            *(const float4*)(Wq + (size_t)(d0 + r) * 256 + ec + (c4 << 2));
      }
      {                                 // pe analytic: (b2, 16 e's)/thread
        int b2 = t >> 3, e0 = (t & 7) << 4;
        #pragma unroll
        for (int k = 0; k < 16; ++k) {
          int e = e0 + k;               // within chunk
          int ge = ec + e;
          int k2 = ge & ~1;             // arange value 2k
          float div = expf((float)k2 * (-9.210340371976184f / 256.f));
          float a = (float)b2 * div;
          pe_s[b2][e] = (ge & 1) ? cosf(a) : sinf(a);
        }
      }
      __syncthreads();
      #pragma unroll 8
      for (int e4 = 0; e4 < 32; ++e4) {
        float4 p = *(const float4*)&pe_s[b][e4 << 2];
        #pragma unroll
        for (int r = 0; r < 4; ++r) {
          float4 w = *(const float4*)&wq_s[(dq << 2) + r][e4 << 2];
          acc[r] += w.x * p.x + w.y * p.y + w.z * p.z + w.w * p.w;
        }
      }
      __syncthreads();
    }
    #pragma unroll
    for (int r = 0; r < 4; ++r)         // 4 scalar stores/thread (1K/block)
      ws[WS_PQ + b * 256 + d0 + (dq << 2) + r] = acc[r];
  }
}

// ---------------------------------------------------------------------------
// K2: U[h][e][j] and V[b][h][e].  512 blocks x 256.  (r6 version, unchanged)
__global__ void __launch_bounds__(256)
k_uv(const float* __restrict__ Wk, const float* __restrict__ bq,
     float* __restrict__ ws) {
  int bid = blockIdx.x, t = threadIdx.x;
  if (bid < 256) {
    int h = bid >> 5, e0 = (bid & 31) << 3;
    __shared__ float wk_s[32][9];       // [d in h][e0..e0+7], +1 pad
    {
      int d = t >> 3, i = t & 7;        // 256 threads cover 32x8
      wk_s[d][i] = Wk[(size_t)(h * 32 + d) * 256 + e0 + i];
    }
    __syncthreads();
    float acc[8] = {0.f, 0.f, 0.f, 0.f, 0.f, 0.f, 0.f, 0.f};
    const float* __restrict__ Qw = ws + WS_QWT + t;
    #pragma unroll 4
    for (int d = 0; d < 32; ++d) {
      float q = Qw[((h << 5) + d) << 8];  // coalesced; wk_s broadcast
      #pragma unroll
      for (int i = 0; i < 8; ++i) acc[i] += wk_s[d][i] * q;
    }
    float* Uh = ws + WS_U + (h << 16) + (size_t)e0 * 256;
    #pragma unroll
    for (int i = 0; i < 8; ++i) Uh[(size_t)i * 256 + t] = acc[i];
  } else {
    int idx = bid - 256, b = idx >> 3, h = idx & 7;
    float acc = 0.f;
#pragma unroll 8
    for (int dd = 0; dd < 32; ++dd) {
      int d = h * 32 + dd;
      acc += (ws[WS_PQ + b * 256 + d] + bq[d]) * Wk[(size_t)d * 256 + t];
    }
    ws[WS_V + ((b << 3) + h) * 256 + t] = acc;
  }
}

// ---------------------------------------------------------------------------
// K3: delta + ALL output. 14592 blocks x 256. (r11 version; dead P store cut)
//   [0,256):        delta compute (b, j-tile32) + merge cols + atten diag
//   [256,2304):     new_state identity half (state cols 0..255)
//   [2304,14592):   atten static (one-hot l<256; zeros l>=256 minus diag f4s)
__global__ void __launch_bounds__(256)
k_delta(const float* __restrict__ state, const float* __restrict__ obs,
        float* __restrict__ ws, float* __restrict__ out) {
  int bid = blockIdx.x, t = threadIdx.x;
  if (bid < 256) {
    int b = bid >> 3, jt = (bid & 7) << 5;
    __shared__ float Xs[256][33];       // X[e][j], +1 pad -> <=2-way (free)
    __shared__ float Vs[2048];          // V[b][h][e] slice
    __shared__ float pd[8][8][32];      // [eg][h][j] partial sum X*w
    __shared__ float pw[8][8][32];      // [eg][h][j] partial sum w
    __shared__ float px[8][32];         // [eg][j]    partial sum X (reused)
    __shared__ float pfin[32];          // final p[b, jt+j]
    {                                   // stage: (es 0..31, jq 0..7) float4
      int es = t >> 3, jq = t & 7;
      const float* sp = state + (size_t)b * 131072 + 256 + jt + (jq << 2);
      const float* op = obs   + (size_t)b * 65536  + jt + (jq << 2);
      #pragma unroll
      for (int k = 0; k < 8; ++k) {
        int e = es + (k << 5);
        float4 s4 = *(const float4*)(sp + (size_t)e * 512);
        float4 o4 = *(const float4*)(op + (size_t)e * 256);
        float* xr = &Xs[e][jq << 2];
        xr[0] = s4.x - o4.x; xr[1] = s4.y - o4.y;
        xr[2] = s4.z - o4.z; xr[3] = s4.w - o4.w;
      }
      for (int i = t; i < 2048; i += 256) Vs[i] = ws[WS_V + (b << 11) + i];
    }
    __syncthreads();
    int j = t & 31, eg = t >> 5, e0 = eg << 5;
    {                                   // a_x partial (h-independent)
      float ax = 0.f;
      #pragma unroll
      for (int ei = 0; ei < 32; ++ei) ax += Xs[e0 + ei][j];
      px[eg][j] = ax;
    }
    const float* __restrict__ Ub = ws + WS_U + jt + j;
    #pragma unroll
    for (int h = 0; h < 8; ++h) {
      float dacc = 0.f, wacc = 0.f;
      const float* __restrict__ Uh = Ub + (h << 16) + (e0 << 8);
      const float* __restrict__ Vh = Vs + (h << 8) + e0;
      #pragma unroll 16
      for (int ei = 0; ei < 32; ++ei) {
        float w = Uh[ei << 8] + Vh[ei];
        dacc += Xs[e0 + ei][j] * w;
        wacc += w;
      }
      pd[eg][h][j] = dacc;
      pw[eg][h][j] = wacc;
    }
    __syncthreads();
    int h2 = t >> 5, j2 = t & 31;       // thread -> (h, j) for the merge
    float D = 0.f, W = 0.f, X = 0.f;
    #pragma unroll
    for (int g = 0; g < 8; ++g) {
      D += pd[g][h2][j2];
      W += pw[g][h2][j2];
      X += px[g][j2];
    }
    float delta = D - X * (1.f / 256.f) * W;
    float sig = 1.f / (1.f + __expf(-delta * 0.17677669529663687f)); // /sqrt(32)
    __syncthreads();
    px[h2][j2] = sig;                   // reuse px as [h][j] sigmoid buffer
    __syncthreads();
    if (t < 32) {
      float acc = 0.f;
      #pragma unroll
      for (int h = 0; h < 8; ++h) acc += px[h][t];
      float p = acc * 0.125f;
      pfin[t] = p;
      // atten diagonal: row l = 256+jt+t, f4 c1 = l>>2 (s=l), c2 = c1+64
      int l = 256 + jt + t;
      size_t rb = 4194304 + (size_t)((b << 9) + l) * 768;
      int c1 = l >> 2, pos = l & 3;
      float v1[4] = {0.f, 0.f, 0.f, 0.f}; v1[pos] = p;
      nt_store4(out + rb + (c1 << 2), v1[0], v1[1], v1[2], v1[3]);
      float v2[4] = {0.f, 0.f, 0.f, 0.f}; v2[pos] = 1.f - p;
      nt_store4(out + rb + ((c1 + 64) << 2), v2[0], v2[1], v2[2], v2[3]);
    }
    __syncthreads();
    // Fused merge: new_state[b, e, 256+jt+j] = o + p*X.
    {
      int eb = t >> 3, j0 = (t & 7) << 2;
      const float* op2 = obs + (size_t)b * 65536 + jt + j0;
      float p0 = pfin[j0], p1 = pfin[j0 + 1], p2 = pfin[j0 + 2], p3 = pfin[j0 + 3];
      float* orow = out + (size_t)b * 131072 + 256 + jt + j0;
      #pragma unroll
      for (int k = 0; k < 8; ++k) {
        int e = eb + (k << 5);
        float4 o4 = *(const float4*)(op2 + (size_t)e * 256);
        const float* xr = &Xs[e][j0];
        nt_store4(orow + (size_t)e * 512,
                  o4.x + p0 * xr[0], o4.y + p1 * xr[1],
                  o4.z + p2 * xr[2], o4.w + p3 * xr[3]);
      }
    }
  } else if (bid < 2304) {              // new_state[b,e,0..255] = state
    int row = ((bid - 256) << 2) | (t >> 6);  // row = b*256 + e
    int c = t & 63;                     // f4 col in lower half
    float4 sv = ((const float4*)(state + (size_t)row * 512))[c];
    nt_store4(out + (size_t)row * 512 + (c << 2), sv.x, sv.y, sv.z, sv.w);
  } else {                              // atten static, one float4 per thread
    int g4 = (bid - 2304) * 256 + t;    // 0..3145727
    int r = g4 / 192, c = g4 - r * 192; // r = b*512 + l
    int b = r >> 9, l = r & 511;
    int s0 = c << 2;
    if (l < 256) {                      // one-hot at s=l (P-independent)
      float v[4] = {0.f, 0.f, 0.f, 0.f};
      if (l >= s0 && l < s0 + 4) v[l - s0] = 1.0f;
      nt_store4(out + 4194304 + ((size_t)g4 << 2), v[0], v[1], v[2], v[3]);
    } else {                            // zeros, skipping the 2 diag f4s
      int c1 = l >> 2;                  // s=l f4 (64..127); c2 = c1+64
      if (c != c1 && c != c1 + 64)
        nt_store4(out + 4194304 + ((size_t)g4 << 2), 0.f, 0.f, 0.f, 0.f);
    }
  }
}

extern "C" void kernel_launch(void* const* d_in, const int* in_sizes, int n_in,
                              void* d_out, int out_size, void* d_ws, size_t ws_size,
                              hipStream_t stream) {
  const float *state = nullptr, *obs = nullptr, *Qp = nullptr;
  const float *Wq = nullptr, *Wk = nullptr, *bq = nullptr, *bk = nullptr;
  for (int i = 0; i < n_in; ++i) {
    int s = in_sizes[i];
    const float* p = (const float*)d_in[i];
    if      (s == 4194304) state = p;
    else if (s == 2097152) obs = p;
    else if (s == 131072)  Qp = p;
    else if (s == 65536)   { if (!Wq) Wq = p; else Wk = p; }
    else if (s == 256)     { if (!bq) bq = p; else bk = p; }
  }
  (void)bk;                             // cancels in the 2-way softmax
  float* out = (float*)d_out;
  float* ws  = (float*)d_ws;

  k_qw   <<<72,    256, 0, stream>>>(Qp, Wq, ws);
  k_uv   <<<512,   256, 0, stream>>>(Wk, bq, ws);
  k_delta<<<14592, 256, 0, stream>>>(state, obs, ws, out);
}